// Round 8
// baseline (1124.082 us; speedup 1.0000x reference)
//
#include <hip/hip_runtime.h>
#include <hip/hip_bf16.h>
#include <hip/hip_fp16.h>

#define NN   100000
#define EE   1600000
#define ETOT (EE + NN)
#define GG   256
#define BNEPS 1e-5f
#define NBK  391          // buckets of 256 nodes: (NN+255)/256
#define PADTOT (ETOT + NBK * 2048 + 64)

typedef float floatx2 __attribute__((ext_vector_type(2)));

// ---------------- CSR build: bucketed partition (single-writer cache lines) --

__global__ __launch_bounds__(256) void bucket_count_kernel(
    const int* __restrict__ ei, int* __restrict__ bucket_cnt)
{
    __shared__ int cnt[NBK];
    for (int i = threadIdx.x; i < NBK; i += 256) cnt[i] = 0;
    __syncthreads();
    int base = blockIdx.x * 8192;
    for (int k = threadIdx.x; k < 8192; k += 256) {
        int e = base + k;
        if (e < ETOT) {
            int dst = (e < EE) ? ei[EE + e] : (e - EE);
            atomicAdd(&cnt[dst >> 8], 1);
        }
    }
    __syncthreads();
    for (int i = threadIdx.x; i < NBK; i += 256)
        if (cnt[i]) atomicAdd(&bucket_cnt[i], cnt[i]);
}

__global__ __launch_bounds__(512) void bucket_scan_kernel(
    const int* __restrict__ bucket_cnt, int* __restrict__ bucket_base,
    int* __restrict__ gcursor)
{
    __shared__ int s[512];
    int t = threadIdx.x;
    int v = (t < NBK) ? bucket_cnt[t] : 0;
    s[t] = v;
    __syncthreads();
    int x = v;
    for (int o = 1; o < 512; o <<= 1) {
        int y = (t >= o) ? s[t - o] : 0;
        __syncthreads();
        x += y;
        s[t] = x;
        __syncthreads();
    }
    if (t < NBK) { bucket_base[t] = x - v; gcursor[t] = x - v; }
    if (t == 0) bucket_base[NBK] = ETOT;
}

__global__ __launch_bounds__(256) void partition_kernel(
    const int* __restrict__ ei, int* __restrict__ gcursor, int* __restrict__ part)
{
    __shared__ int cnt[NBK];
    __shared__ int basel[NBK];
    for (int i = threadIdx.x; i < NBK; i += 256) cnt[i] = 0;
    __syncthreads();
    int base = blockIdx.x * 4096;
    for (int k = threadIdx.x; k < 4096; k += 256) {
        int e = base + k;
        if (e < ETOT) {
            int dst = (e < EE) ? ei[EE + e] : (e - EE);
            atomicAdd(&cnt[dst >> 8], 1);
        }
    }
    __syncthreads();
    for (int i = threadIdx.x; i < NBK; i += 256) {
        int c = cnt[i];
        basel[i] = c ? atomicAdd(&gcursor[i], c) : 0;
        cnt[i] = 0;   // reuse as intra-block cursor
    }
    __syncthreads();
    for (int k = threadIdx.x; k < 4096; k += 256) {
        int e = base + k;
        if (e < ETOT) {
            int src, dst;
            if (e < EE) { src = ei[e]; dst = ei[EE + e]; }
            else        { src = e - EE; dst = e - EE; }
            int b = dst >> 8;
            int slot = atomicAdd(&cnt[b], 1);
            part[basel[b] + slot] = src | ((dst & 255) << 17);
        }
    }
}

// Padded CSR: per-node segments rounded up to 8 entries (pad src = 0),
// 8-aligned starts → aggregate loop needs no masking and can use int4 loads.
__global__ __launch_bounds__(256) void csr_build_kernel(
    const int* __restrict__ part, const int* __restrict__ bucket_base,
    int* __restrict__ row2_start, int* __restrict__ row2_deg,
    int* __restrict__ csr2_src)
{
    __shared__ int degs[256];
    __shared__ int sc[256];
    __shared__ int cur[256];
    int b = blockIdx.x;
    int t = threadIdx.x;
    int beg = bucket_base[b], end = bucket_base[b + 1];
    int pbase = ((beg + 7) & ~7) + 2048 * b;
    degs[t] = 0;
    __syncthreads();
    for (int j = beg + t; j < end; j += 256)
        atomicAdd(&degs[(part[j] >> 17) & 255], 1);
    __syncthreads();
    int dg = degs[t];
    int pdeg = (dg + 7) & ~7;
    sc[t] = pdeg;
    __syncthreads();
    int x = pdeg;
    for (int o = 1; o < 256; o <<= 1) {
        int y = (t >= o) ? sc[t - o] : 0;
        __syncthreads();
        x += y;
        sc[t] = x;
        __syncthreads();
    }
    int start2 = pbase + (x - pdeg);
    int node = b * 256 + t;
    if (node < NN) { row2_start[node] = start2; row2_deg[node] = dg; }
    cur[t] = start2;
    __syncthreads();
    for (int j = beg + t; j < end; j += 256) {
        int pv = part[j];
        int pos = atomicAdd(&cur[(pv >> 17) & 255], 1);
        csr2_src[pos] = pv & 0x1FFFF;
    }
    // fill pad slots with src=0 (weight will be 0)
    for (int k = dg; k < pdeg; ++k) csr2_src[start2 + k] = 0;
}

// ---------------- per-layer edge softmax weights (both heads, fp32) ----------
// One wave per dst node, lane per edge. esrc table is 800 KB → L2-resident.

__global__ __launch_bounds__(256) void edgew_kernel(
    const int* __restrict__ csr2_src, const int* __restrict__ row2_start,
    const int* __restrict__ row2_deg,
    const float2* __restrict__ esrc, const float2* __restrict__ edst,
    float2* __restrict__ csr_w, int nN)
{
    int n = blockIdx.x * 4 + (threadIdx.x >> 6);
    int lane = threadIdx.x & 63;
    if (n >= nN) return;
    float2 ed = edst[n];
    int s2 = row2_start[n];
    int dg = row2_deg[n];
    int pc = (dg + 7) & ~7;
    for (int j = lane; j < pc; j += 64) {
        float2 w = make_float2(0.f, 0.f);
        if (j < dg) {
            int i = csr2_src[s2 + j];
            float2 es = esrc[i];
            float a0 = es.x + ed.x; a0 = (a0 > 0.f) ? a0 : 0.2f * a0;
            float a1 = es.y + ed.y; a1 = (a1 > 0.f) ? a1 : 0.2f * a1;
            w.x = __expf(a0);
            w.y = __expf(a1);
        }
        csr_w[s2 + j] = w;
    }
}

// ---------------- layer-1 feature transform (K=5); h stored fp8 e4m3 ---------

__global__ __launch_bounds__(256) void feat1_kernel(
    const float* __restrict__ xin, const float* __restrict__ W,
    const float* __restrict__ pw, const float* __restrict__ pb,
    const float* __restrict__ a_src, const float* __restrict__ a_dst,
    unsigned char* __restrict__ h8, float* __restrict__ esrc, float* __restrict__ edst,
    float* __restrict__ rout, int nN)
{
    constexpr int F_IN = 5, F_OUT = 64;
    int t = threadIdx.x;
    int n = blockIdx.x * 4 + t / F_OUT;
    int f = t % F_OUT;
    if (n >= nN) return;
    float acc = 0.f, racc = 0.f;
#pragma unroll
    for (int k = 0; k < F_IN; ++k) {
        float xv = xin[n * F_IN + k];
        acc  += xv * W[k * F_OUT + f];
        racc += xv * pw[k * F_OUT + f];
    }
    float other = __shfl_xor(acc, 1, 64);
    if ((f & 1) == 0) {
        int p = __builtin_amdgcn_cvt_pk_fp8_f32(acc, other, 0, false);
        *(unsigned short*)(h8 + (size_t)n * F_OUT + f) = (unsigned short)(p & 0xFFFF);
    }
    rout[(size_t)n * F_OUT + f] = racc + pb[f];
    float es = acc * a_src[f];
    float ed = acc * a_dst[f];
#pragma unroll
    for (int off = 16; off > 0; off >>= 1) {
        es += __shfl_xor(es, off, 32);
        ed += __shfl_xor(ed, off, 32);
    }
    if ((t & 31) == 0) {
        int head = (f >> 5) & 1;
        esrc[n * 2 + head] = es;
        edst[n * 2 + head] = ed;
    }
}

// ---------------- register-tiled feature transform (layers 2,3; F_OUT=128) ----

template<int F_IN>
__global__ __launch_bounds__(256, 4) void tiled_feat_kernel(
    const float* __restrict__ xin, const float* __restrict__ W,
    const float* __restrict__ pw, const float* __restrict__ pb,
    const float* __restrict__ a_src, const float* __restrict__ a_dst,
    unsigned char* __restrict__ h8, float* __restrict__ esrc, float* __restrict__ edst,
    float* __restrict__ rout)
{
    constexpr int F_OUT = 128;
    constexpr int TILE_M = 32;
    constexpr int K4 = F_IN / 4;
    __shared__ float4 xs4[TILE_M * K4];

    const int tid = threadIdx.x;
    const int cg  = tid & 63;
    const int g   = tid >> 6;
    const int base = blockIdx.x * TILE_M;

    constexpr int NV = TILE_M * K4;
    const float4* xg4 = (const float4*)xin;
    const int maxv = NN * K4 - 1;
#pragma unroll
    for (int i = tid; i < NV; i += 256) {
        int gi = base * K4 + i;
        xs4[i] = xg4[gi <= maxv ? gi : maxv];
    }
    __syncthreads();

    const int col4 = cg * 4;
    const bool isW = (col4 < F_OUT);
    const float* wbase = isW ? W : pw;
    const int f = isW ? col4 : (col4 - F_OUT);

    float4 acc[8];
#pragma unroll
    for (int i = 0; i < 8; ++i) acc[i] = make_float4(0.f, 0.f, 0.f, 0.f);

    for (int k0 = 0; k0 < F_IN; k0 += 4) {
        float4 w0 = *(const float4*)(wbase + (size_t)(k0 + 0) * F_OUT + f);
        float4 w1 = *(const float4*)(wbase + (size_t)(k0 + 1) * F_OUT + f);
        float4 w2 = *(const float4*)(wbase + (size_t)(k0 + 2) * F_OUT + f);
        float4 w3 = *(const float4*)(wbase + (size_t)(k0 + 3) * F_OUT + f);
#pragma unroll
        for (int i = 0; i < 8; ++i) {
            float4 xv = xs4[(g * 8 + i) * K4 + (k0 >> 2)];
            acc[i].x = fmaf(xv.x, w0.x, acc[i].x);
            acc[i].y = fmaf(xv.x, w0.y, acc[i].y);
            acc[i].z = fmaf(xv.x, w0.z, acc[i].z);
            acc[i].w = fmaf(xv.x, w0.w, acc[i].w);
            acc[i].x = fmaf(xv.y, w1.x, acc[i].x);
            acc[i].y = fmaf(xv.y, w1.y, acc[i].y);
            acc[i].z = fmaf(xv.y, w1.z, acc[i].z);
            acc[i].w = fmaf(xv.y, w1.w, acc[i].w);
            acc[i].x = fmaf(xv.z, w2.x, acc[i].x);
            acc[i].y = fmaf(xv.z, w2.y, acc[i].y);
            acc[i].z = fmaf(xv.z, w2.z, acc[i].z);
            acc[i].w = fmaf(xv.z, w2.w, acc[i].w);
            acc[i].x = fmaf(xv.w, w3.x, acc[i].x);
            acc[i].y = fmaf(xv.w, w3.y, acc[i].y);
            acc[i].z = fmaf(xv.w, w3.z, acc[i].z);
            acc[i].w = fmaf(xv.w, w3.w, acc[i].w);
        }
    }

    if (isW) {
        float4 av = *(const float4*)(a_src + f);
        float4 dv = *(const float4*)(a_dst + f);
        int head = cg >> 4;
#pragma unroll
        for (int i = 0; i < 8; ++i) {
            int node = base + g * 8 + i;
            if (node < NN) {
                int p = __builtin_amdgcn_cvt_pk_fp8_f32(acc[i].x, acc[i].y, 0, false);
                p = __builtin_amdgcn_cvt_pk_fp8_f32(acc[i].z, acc[i].w, p, true);
                *(int*)(h8 + (size_t)node * F_OUT + f) = p;
            }
            float es = acc[i].x * av.x + acc[i].y * av.y + acc[i].z * av.z + acc[i].w * av.w;
            float ed = acc[i].x * dv.x + acc[i].y * dv.y + acc[i].z * dv.z + acc[i].w * dv.w;
#pragma unroll
            for (int off = 8; off > 0; off >>= 1) {
                es += __shfl_xor(es, off, 16);
                ed += __shfl_xor(ed, off, 16);
            }
            if ((cg & 15) == 0 && node < NN) {
                esrc[node * 2 + head] = es;
                edst[node * 2 + head] = ed;
            }
        }
    } else {
        float4 bv = *(const float4*)(pb + f);
#pragma unroll
        for (int i = 0; i < 8; ++i) {
            int node = base + g * 8 + i;
            if (node < NN) {
                float4 r = acc[i];
                r.x += bv.x; r.y += bv.y; r.z += bv.z; r.w += bv.w;
                *(float4*)(rout + (size_t)node * F_OUT + f) = r;
            }
        }
    }
}

// ---------------- fused aggregate, F=128 (fp8 h, padded CSR, precomputed w) --
// No masking, no expf in the loop: 6 uniform int4/float4 loads + 8 gathers
// per 8 edges; ~15 VALU instr/edge (R7 measured ~58 → the bound).

__global__ __launch_bounds__(256) void aggregate128_kernel(
    const unsigned short* __restrict__ h8s,
    const int* __restrict__ row2_start, const int* __restrict__ row2_deg,
    const int* __restrict__ csr2_src, const float2* __restrict__ csr_w,
    const float* __restrict__ bias, const float* __restrict__ bng,
    const float* __restrict__ bnb, const float* __restrict__ bnm,
    const float* __restrict__ bnv, float* __restrict__ out, int nN)
{
    int w = threadIdx.x >> 6;
    int lane = threadIdx.x & 63;
    int n = blockIdx.x * 4 + w;
    if (n >= nN) return;
    bool hi = lane >= 32;
    int s2 = row2_start[n];
    int dg = row2_deg[n];
    int pc = (dg + 7) & ~7;
    const int4* sp = (const int4*)(csr2_src + s2);
    const float4* wp = (const float4*)(csr_w + s2);
    float s = 0.f, ax = 0.f, ay = 0.f;
    for (int j = 0; j < pc; j += 8) {
        int idx[8];
        *(int4*)&idx[0] = sp[(j >> 2) + 0];
        *(int4*)&idx[4] = sp[(j >> 2) + 1];
        float2 wv[8];
        *(float4*)&wv[0] = wp[(j >> 1) + 0];
        *(float4*)&wv[2] = wp[(j >> 1) + 1];
        *(float4*)&wv[4] = wp[(j >> 1) + 2];
        *(float4*)&wv[6] = wp[(j >> 1) + 3];
        unsigned short v[8];
#pragma unroll
        for (int u = 0; u < 8; ++u) v[u] = h8s[(size_t)idx[u] * 64 + lane];
#pragma unroll
        for (int u = 0; u < 8; ++u) {
            float wgt = hi ? wv[u].y : wv[u].x;
            floatx2 f = __builtin_amdgcn_cvt_pk_f32_fp8((int)v[u], false);
            ax = fmaf(wgt, f.x, ax);
            ay = fmaf(wgt, f.y, ay);
            s += wgt;
        }
    }
    float inv = 1.f / (s + 1e-16f);
    int f0i = 2 * lane, f1i = 2 * lane + 1;
    float g0 = ax * inv, g1 = ay * inv;
    float o0 = bng[f0i] * (g0 + bias[f0i] - bnm[f0i]) * rsqrtf(bnv[f0i] + BNEPS) + bnb[f0i];
    float o1 = bng[f1i] * (g1 + bias[f1i] - bnm[f1i]) * rsqrtf(bnv[f1i] + BNEPS) + bnb[f1i];
    float2* op = (float2*)(out + (size_t)n * 128) + lane;
    float2 prev = *op;
    prev.x += fmaxf(o0, 0.f);
    prev.y += fmaxf(o1, 0.f);
    *op = prev;
}

// ---------------- fused aggregate, F=64 ---------------------------------------

__global__ __launch_bounds__(256) void aggregate64_kernel(
    const unsigned char* __restrict__ h8,
    const int* __restrict__ row2_start, const int* __restrict__ row2_deg,
    const int* __restrict__ csr2_src, const float2* __restrict__ csr_w,
    const float* __restrict__ bias, const float* __restrict__ bng,
    const float* __restrict__ bnb, const float* __restrict__ bnm,
    const float* __restrict__ bnv, float* __restrict__ out, int nN)
{
    int w = threadIdx.x >> 6;
    int lane = threadIdx.x & 63;
    int n = blockIdx.x * 4 + w;
    if (n >= nN) return;
    bool hi = lane >= 32;
    int s2 = row2_start[n];
    int dg = row2_deg[n];
    int pc = (dg + 7) & ~7;
    const int4* sp = (const int4*)(csr2_src + s2);
    const float4* wp = (const float4*)(csr_w + s2);
    float s = 0.f, acc = 0.f;
    for (int j = 0; j < pc; j += 8) {
        int idx[8];
        *(int4*)&idx[0] = sp[(j >> 2) + 0];
        *(int4*)&idx[4] = sp[(j >> 2) + 1];
        float2 wv[8];
        *(float4*)&wv[0] = wp[(j >> 1) + 0];
        *(float4*)&wv[2] = wp[(j >> 1) + 1];
        *(float4*)&wv[4] = wp[(j >> 1) + 2];
        *(float4*)&wv[6] = wp[(j >> 1) + 3];
        unsigned char v[8];
#pragma unroll
        for (int u = 0; u < 8; ++u) v[u] = h8[(size_t)idx[u] * 64 + lane];
#pragma unroll
        for (int u = 0; u < 8; ++u) {
            float wgt = hi ? wv[u].y : wv[u].x;
            float fv = __builtin_amdgcn_cvt_f32_fp8((int)v[u], 0);
            acc = fmaf(wgt, fv, acc);
            s += wgt;
        }
    }
    int f = lane;
    float g = acc / (s + 1e-16f);
    float vv = bng[f] * (g + bias[f] - bnm[f]) * rsqrtf(bnv[f] + BNEPS) + bnb[f];
    out[(size_t)n * 64 + f] = fmaxf(vv, 0.f) + out[(size_t)n * 64 + f];
}

// ---------------- pooling (segment mean over sorted batch) ----------------

__global__ __launch_bounds__(128) void pool_kernel(const float* __restrict__ hfin,
                                                   const int* __restrict__ batch,
                                                   float* __restrict__ pooled) {
    int g = blockIdx.x;
    int f = threadIdx.x;
    int lo = 0, hi = NN;
    while (lo < hi) { int mid = (lo + hi) >> 1; if (batch[mid] < g) lo = mid + 1; else hi = mid; }
    int start = lo;
    hi = NN;
    while (lo < hi) { int mid = (lo + hi) >> 1; if (batch[mid] < g + 1) lo = mid + 1; else hi = mid; }
    int end = lo;
    float acc = 0.f;
    for (int i = start; i < end; ++i) acc += hfin[(size_t)i * 128 + f];
    float cnt = (float)(end - start);
    pooled[g * 128 + f] = acc / fmaxf(cnt, 1.0f);
}

// ---------------- MLP head ----------------

__global__ __launch_bounds__(128) void head_kernel(
    const float* __restrict__ pooled, const float* __restrict__ fw, const float* __restrict__ fb,
    const float* __restrict__ g4, const float* __restrict__ be4,
    const float* __restrict__ m4, const float* __restrict__ v4,
    const float* __restrict__ l1w, const float* __restrict__ l1b,
    const float* __restrict__ l2w, const float* __restrict__ l2b,
    float* __restrict__ out)
{
    __shared__ float p[128];
    __shared__ float z1[32];
    __shared__ float z2[32];
    int g = blockIdx.x, t = threadIdx.x;
    p[t] = pooled[g * 128 + t];
    __syncthreads();
    if (t < 32) {
        float acc = fb[t];
        for (int k = 0; k < 128; ++k) acc += p[k] * fw[k * 32 + t];
        float val = g4[t] * (acc - m4[t]) * rsqrtf(v4[t] + BNEPS) + be4[t];
        z1[t] = fmaxf(val, 0.f);
    }
    __syncthreads();
    if (t < 32) {
        float acc = l1b[t];
        for (int k = 0; k < 32; ++k) acc += z1[k] * l1w[k * 32 + t];
        z2[t] = fmaxf(acc, 0.f);
    }
    __syncthreads();
    if (t < 10) {
        float acc = l2b[t];
        for (int k = 0; k < 32; ++k) acc += z2[k] * l2w[k * 10 + t];
        out[g * 10 + t] = acc;
    }
}

// ---------------- launch ----------------

extern "C" void kernel_launch(void* const* d_in, const int* in_sizes, int n_in,
                              void* d_out, int out_size, void* d_ws, size_t ws_size,
                              hipStream_t stream) {
    const float* x     = (const float*)d_in[0];
    const int*   ei    = (const int*)d_in[1];
    const int*   batch = (const int*)d_in[2];
    const float* w1  = (const float*)d_in[3];
    const float* as1 = (const float*)d_in[4];
    const float* ad1 = (const float*)d_in[5];
    const float* b1  = (const float*)d_in[6];
    const float* g1  = (const float*)d_in[7];
    const float* be1 = (const float*)d_in[8];
    const float* m1  = (const float*)d_in[9];
    const float* v1  = (const float*)d_in[10];
    const float* p1w = (const float*)d_in[11];
    const float* p1b = (const float*)d_in[12];
    const float* w2  = (const float*)d_in[13];
    const float* as2 = (const float*)d_in[14];
    const float* ad2 = (const float*)d_in[15];
    const float* b2  = (const float*)d_in[16];
    const float* g2  = (const float*)d_in[17];
    const float* be2 = (const float*)d_in[18];
    const float* m2  = (const float*)d_in[19];
    const float* v2  = (const float*)d_in[20];
    const float* p2w = (const float*)d_in[21];
    const float* p2b = (const float*)d_in[22];
    const float* w3  = (const float*)d_in[23];
    const float* as3 = (const float*)d_in[24];
    const float* ad3 = (const float*)d_in[25];
    const float* b3  = (const float*)d_in[26];
    const float* g3  = (const float*)d_in[27];
    const float* be3 = (const float*)d_in[28];
    const float* m3  = (const float*)d_in[29];
    const float* v3  = (const float*)d_in[30];
    const float* p3w = (const float*)d_in[31];
    const float* p3b = (const float*)d_in[32];
    const float* fw  = (const float*)d_in[33];
    const float* fb  = (const float*)d_in[34];
    const float* g4  = (const float*)d_in[35];
    const float* be4 = (const float*)d_in[36];
    const float* m4  = (const float*)d_in[37];
    const float* v4  = (const float*)d_in[38];
    const float* l1w = (const float*)d_in[39];
    const float* l1b = (const float*)d_in[40];
    const float* l2w = (const float*)d_in[41];
    const float* l2b = (const float*)d_in[42];

    char* ws = (char*)d_ws;
    size_t off = 0;
    auto alloc = [&](size_t bytes) -> char* {
        char* p = ws + off;
        off += (bytes + 255) & ~(size_t)255;
        return p;
    };
    int*    bucket_cnt  = (int*)alloc((NBK) * sizeof(int));
    int*    bucket_base = (int*)alloc((NBK + 1) * sizeof(int));
    int*    gcursor     = (int*)alloc((NBK) * sizeof(int));
    int*    part        = (int*)alloc((size_t)ETOT * sizeof(int));
    int*    row2_start  = (int*)alloc(NN * sizeof(int));
    int*    row2_deg    = (int*)alloc(NN * sizeof(int));
    int*    csr2_src    = (int*)alloc((size_t)PADTOT * sizeof(int));
    float2* csr_w       = (float2*)alloc((size_t)PADTOT * sizeof(float2));
    unsigned char* h8   = (unsigned char*)alloc((size_t)NN * 128);
    float*  bufB        = (float*)alloc((size_t)NN * 128 * sizeof(float));
    float*  bufC        = (float*)alloc((size_t)NN * 128 * sizeof(float));
    float*  esrc        = (float*)alloc((size_t)NN * 2 * sizeof(float));
    float*  edst        = (float*)alloc((size_t)NN * 2 * sizeof(float));
    float*  pooled      = (float*)alloc((size_t)GG * 128 * sizeof(float));

    // ---- CSR build (bucketed partition, padded layout) ----
    hipMemsetAsync(bucket_cnt, 0, NBK * sizeof(int), stream);
    bucket_count_kernel<<<(ETOT + 8191) / 8192, 256, 0, stream>>>(ei, bucket_cnt);
    bucket_scan_kernel<<<1, 512, 0, stream>>>(bucket_cnt, bucket_base, gcursor);
    partition_kernel<<<(ETOT + 4095) / 4096, 256, 0, stream>>>(ei, gcursor, part);
    csr_build_kernel<<<NBK, 256, 0, stream>>>(part, bucket_base, row2_start, row2_deg, csr2_src);

    // ---- layer 1: x[N,5] -> bufB[N,64] ----
    feat1_kernel<<<(NN + 3) / 4, 256, 0, stream>>>(
        x, w1, p1w, p1b, as1, ad1, h8, esrc, edst, bufB, NN);
    edgew_kernel<<<(NN + 3) / 4, 256, 0, stream>>>(
        csr2_src, row2_start, row2_deg, (const float2*)esrc, (const float2*)edst, csr_w, NN);
    aggregate64_kernel<<<(NN + 3) / 4, 256, 0, stream>>>(
        h8, row2_start, row2_deg, csr2_src, csr_w,
        b1, g1, be1, m1, v1, bufB, NN);

    // ---- layer 2: bufB[N,64] -> bufC[N,128] ----
    tiled_feat_kernel<64><<<(NN + 31) / 32, 256, 0, stream>>>(
        bufB, w2, p2w, p2b, as2, ad2, h8, esrc, edst, bufC);
    edgew_kernel<<<(NN + 3) / 4, 256, 0, stream>>>(
        csr2_src, row2_start, row2_deg, (const float2*)esrc, (const float2*)edst, csr_w, NN);
    aggregate128_kernel<<<(NN + 3) / 4, 256, 0, stream>>>(
        (const unsigned short*)h8, row2_start, row2_deg, csr2_src, csr_w,
        b2, g2, be2, m2, v2, bufC, NN);

    // ---- layer 3: bufC[N,128] -> bufB[N,128] ----
    tiled_feat_kernel<128><<<(NN + 31) / 32, 256, 0, stream>>>(
        bufC, w3, p3w, p3b, as3, ad3, h8, esrc, edst, bufB);
    edgew_kernel<<<(NN + 3) / 4, 256, 0, stream>>>(
        csr2_src, row2_start, row2_deg, (const float2*)esrc, (const float2*)edst, csr_w, NN);
    aggregate128_kernel<<<(NN + 3) / 4, 256, 0, stream>>>(
        (const unsigned short*)h8, row2_start, row2_deg, csr2_src, csr_w,
        b3, g3, be3, m3, v3, bufB, NN);

    // ---- pool + head ----
    pool_kernel<<<GG, 128, 0, stream>>>(bufB, batch, pooled);
    head_kernel<<<GG, 128, 0, stream>>>(pooled, fw, fb, g4, be4, m4, v4,
                                        l1w, l1b, l2w, l2b, (float*)d_out);
}

// Round 9
// 792.493 us; speedup vs baseline: 1.4184x; 1.4184x over previous
//
#include <hip/hip_runtime.h>
#include <hip/hip_bf16.h>
#include <hip/hip_fp16.h>

#define NN   100000
#define EE   1600000
#define ETOT (EE + NN)
#define GG   256
#define BNEPS 1e-5f
#define NBK  391          // buckets of 256 nodes: (NN+255)/256
#define PADTOT (ETOT + NBK * 2048 + 64)

typedef float floatx2 __attribute__((ext_vector_type(2)));

// ---------------- CSR build: bucketed partition (single-writer cache lines) --

__global__ __launch_bounds__(256) void bucket_count_kernel(
    const int* __restrict__ ei, int* __restrict__ bucket_cnt)
{
    __shared__ int cnt[NBK];
    for (int i = threadIdx.x; i < NBK; i += 256) cnt[i] = 0;
    __syncthreads();
    int base = blockIdx.x * 8192;
    for (int k = threadIdx.x; k < 8192; k += 256) {
        int e = base + k;
        if (e < ETOT) {
            int dst = (e < EE) ? ei[EE + e] : (e - EE);
            atomicAdd(&cnt[dst >> 8], 1);
        }
    }
    __syncthreads();
    for (int i = threadIdx.x; i < NBK; i += 256)
        if (cnt[i]) atomicAdd(&bucket_cnt[i], cnt[i]);
}

__global__ __launch_bounds__(512) void bucket_scan_kernel(
    const int* __restrict__ bucket_cnt, int* __restrict__ bucket_base,
    int* __restrict__ gcursor)
{
    __shared__ int s[512];
    int t = threadIdx.x;
    int v = (t < NBK) ? bucket_cnt[t] : 0;
    s[t] = v;
    __syncthreads();
    int x = v;
    for (int o = 1; o < 512; o <<= 1) {
        int y = (t >= o) ? s[t - o] : 0;
        __syncthreads();
        x += y;
        s[t] = x;
        __syncthreads();
    }
    if (t < NBK) { bucket_base[t] = x - v; gcursor[t] = x - v; }
    if (t == 0) bucket_base[NBK] = ETOT;
}

__global__ __launch_bounds__(256) void partition_kernel(
    const int* __restrict__ ei, int* __restrict__ gcursor, int* __restrict__ part)
{
    __shared__ int cnt[NBK];
    __shared__ int basel[NBK];
    for (int i = threadIdx.x; i < NBK; i += 256) cnt[i] = 0;
    __syncthreads();
    int base = blockIdx.x * 4096;
    for (int k = threadIdx.x; k < 4096; k += 256) {
        int e = base + k;
        if (e < ETOT) {
            int dst = (e < EE) ? ei[EE + e] : (e - EE);
            atomicAdd(&cnt[dst >> 8], 1);
        }
    }
    __syncthreads();
    for (int i = threadIdx.x; i < NBK; i += 256) {
        int c = cnt[i];
        basel[i] = c ? atomicAdd(&gcursor[i], c) : 0;
        cnt[i] = 0;   // reuse as intra-block cursor
    }
    __syncthreads();
    for (int k = threadIdx.x; k < 4096; k += 256) {
        int e = base + k;
        if (e < ETOT) {
            int src, dst;
            if (e < EE) { src = ei[e]; dst = ei[EE + e]; }
            else        { src = e - EE; dst = e - EE; }
            int b = dst >> 8;
            int slot = atomicAdd(&cnt[b], 1);
            part[basel[b] + slot] = src | ((dst & 255) << 17);
        }
    }
}

// Padded CSR: per-node segments rounded up to 8 entries (pad src = 0),
// 8-aligned starts → aggregate loop needs no masking and uses int4 loads.
__global__ __launch_bounds__(256) void csr_build_kernel(
    const int* __restrict__ part, const int* __restrict__ bucket_base,
    int* __restrict__ row2_start, int* __restrict__ row2_deg,
    int* __restrict__ csr2_src)
{
    __shared__ int degs[256];
    __shared__ int sc[256];
    __shared__ int cur[256];
    int b = blockIdx.x;
    int t = threadIdx.x;
    int beg = bucket_base[b], end = bucket_base[b + 1];
    int pbase = ((beg + 7) & ~7) + 2048 * b;
    degs[t] = 0;
    __syncthreads();
    for (int j = beg + t; j < end; j += 256)
        atomicAdd(&degs[(part[j] >> 17) & 255], 1);
    __syncthreads();
    int dg = degs[t];
    int pdeg = (dg + 7) & ~7;
    sc[t] = pdeg;
    __syncthreads();
    int x = pdeg;
    for (int o = 1; o < 256; o <<= 1) {
        int y = (t >= o) ? sc[t - o] : 0;
        __syncthreads();
        x += y;
        sc[t] = x;
        __syncthreads();
    }
    int start2 = pbase + (x - pdeg);
    int node = b * 256 + t;
    if (node < NN) { row2_start[node] = start2; row2_deg[node] = dg; }
    cur[t] = start2;
    __syncthreads();
    for (int j = beg + t; j < end; j += 256) {
        int pv = part[j];
        int pos = atomicAdd(&cur[(pv >> 17) & 255], 1);
        csr2_src[pos] = pv & 0x1FFFF;
    }
    for (int k = dg; k < pdeg; ++k) csr2_src[start2 + k] = 0;
}

// ---------------- per-layer edge softmax weights (both heads, fp32) ----------

__global__ __launch_bounds__(256) void edgew_kernel(
    const int* __restrict__ csr2_src, const int* __restrict__ row2_start,
    const int* __restrict__ row2_deg,
    const float2* __restrict__ esrc, const float2* __restrict__ edst,
    float2* __restrict__ csr_w, int nN)
{
    int n = blockIdx.x * 4 + (threadIdx.x >> 6);
    int lane = threadIdx.x & 63;
    if (n >= nN) return;
    float2 ed = edst[n];
    int s2 = row2_start[n];
    int dg = row2_deg[n];
    int pc = (dg + 7) & ~7;
    for (int j = lane; j < pc; j += 64) {
        float2 w = make_float2(0.f, 0.f);
        if (j < dg) {
            int i = csr2_src[s2 + j];
            float2 es = esrc[i];
            float a0 = es.x + ed.x; a0 = (a0 > 0.f) ? a0 : 0.2f * a0;
            float a1 = es.y + ed.y; a1 = (a1 > 0.f) ? a1 : 0.2f * a1;
            w.x = __expf(a0);
            w.y = __expf(a1);
        }
        csr_w[s2 + j] = w;
    }
}

// ---------------- layer-1 feature transform (K=5); h stored fp8 e4m3 ---------

__global__ __launch_bounds__(256) void feat1_kernel(
    const float* __restrict__ xin, const float* __restrict__ W,
    const float* __restrict__ pw, const float* __restrict__ pb,
    const float* __restrict__ a_src, const float* __restrict__ a_dst,
    unsigned char* __restrict__ h8, float* __restrict__ esrc, float* __restrict__ edst,
    float* __restrict__ rout, int nN)
{
    constexpr int F_IN = 5, F_OUT = 64;
    int t = threadIdx.x;
    int n = blockIdx.x * 4 + t / F_OUT;
    int f = t % F_OUT;
    if (n >= nN) return;
    float acc = 0.f, racc = 0.f;
#pragma unroll
    for (int k = 0; k < F_IN; ++k) {
        float xv = xin[n * F_IN + k];
        acc  += xv * W[k * F_OUT + f];
        racc += xv * pw[k * F_OUT + f];
    }
    float other = __shfl_xor(acc, 1, 64);
    if ((f & 1) == 0) {
        int p = __builtin_amdgcn_cvt_pk_fp8_f32(acc, other, 0, false);
        *(unsigned short*)(h8 + (size_t)n * F_OUT + f) = (unsigned short)(p & 0xFFFF);
    }
    rout[(size_t)n * F_OUT + f] = racc + pb[f];
    float es = acc * a_src[f];
    float ed = acc * a_dst[f];
#pragma unroll
    for (int off = 16; off > 0; off >>= 1) {
        es += __shfl_xor(es, off, 32);
        ed += __shfl_xor(ed, off, 32);
    }
    if ((t & 31) == 0) {
        int head = (f >> 5) & 1;
        esrc[n * 2 + head] = es;
        edst[n * 2 + head] = ed;
    }
}

// ---------------- register-tiled feature transform (layers 2,3; F_OUT=128) ----

template<int F_IN>
__global__ __launch_bounds__(256, 4) void tiled_feat_kernel(
    const float* __restrict__ xin, const float* __restrict__ W,
    const float* __restrict__ pw, const float* __restrict__ pb,
    const float* __restrict__ a_src, const float* __restrict__ a_dst,
    unsigned char* __restrict__ h8, float* __restrict__ esrc, float* __restrict__ edst,
    float* __restrict__ rout)
{
    constexpr int F_OUT = 128;
    constexpr int TILE_M = 32;
    constexpr int K4 = F_IN / 4;
    __shared__ float4 xs4[TILE_M * K4];

    const int tid = threadIdx.x;
    const int cg  = tid & 63;
    const int g   = tid >> 6;
    const int base = blockIdx.x * TILE_M;

    constexpr int NV = TILE_M * K4;
    const float4* xg4 = (const float4*)xin;
    const int maxv = NN * K4 - 1;
#pragma unroll
    for (int i = tid; i < NV; i += 256) {
        int gi = base * K4 + i;
        xs4[i] = xg4[gi <= maxv ? gi : maxv];
    }
    __syncthreads();

    const int col4 = cg * 4;
    const bool isW = (col4 < F_OUT);
    const float* wbase = isW ? W : pw;
    const int f = isW ? col4 : (col4 - F_OUT);

    float4 acc[8];
#pragma unroll
    for (int i = 0; i < 8; ++i) acc[i] = make_float4(0.f, 0.f, 0.f, 0.f);

    for (int k0 = 0; k0 < F_IN; k0 += 4) {
        float4 w0 = *(const float4*)(wbase + (size_t)(k0 + 0) * F_OUT + f);
        float4 w1 = *(const float4*)(wbase + (size_t)(k0 + 1) * F_OUT + f);
        float4 w2 = *(const float4*)(wbase + (size_t)(k0 + 2) * F_OUT + f);
        float4 w3 = *(const float4*)(wbase + (size_t)(k0 + 3) * F_OUT + f);
#pragma unroll
        for (int i = 0; i < 8; ++i) {
            float4 xv = xs4[(g * 8 + i) * K4 + (k0 >> 2)];
            acc[i].x = fmaf(xv.x, w0.x, acc[i].x);
            acc[i].y = fmaf(xv.x, w0.y, acc[i].y);
            acc[i].z = fmaf(xv.x, w0.z, acc[i].z);
            acc[i].w = fmaf(xv.x, w0.w, acc[i].w);
            acc[i].x = fmaf(xv.y, w1.x, acc[i].x);
            acc[i].y = fmaf(xv.y, w1.y, acc[i].y);
            acc[i].z = fmaf(xv.y, w1.z, acc[i].z);
            acc[i].w = fmaf(xv.y, w1.w, acc[i].w);
            acc[i].x = fmaf(xv.z, w2.x, acc[i].x);
            acc[i].y = fmaf(xv.z, w2.y, acc[i].y);
            acc[i].z = fmaf(xv.z, w2.z, acc[i].z);
            acc[i].w = fmaf(xv.z, w2.w, acc[i].w);
            acc[i].x = fmaf(xv.w, w3.x, acc[i].x);
            acc[i].y = fmaf(xv.w, w3.y, acc[i].y);
            acc[i].z = fmaf(xv.w, w3.z, acc[i].z);
            acc[i].w = fmaf(xv.w, w3.w, acc[i].w);
        }
    }

    if (isW) {
        float4 av = *(const float4*)(a_src + f);
        float4 dv = *(const float4*)(a_dst + f);
        int head = cg >> 4;
#pragma unroll
        for (int i = 0; i < 8; ++i) {
            int node = base + g * 8 + i;
            if (node < NN) {
                int p = __builtin_amdgcn_cvt_pk_fp8_f32(acc[i].x, acc[i].y, 0, false);
                p = __builtin_amdgcn_cvt_pk_fp8_f32(acc[i].z, acc[i].w, p, true);
                *(int*)(h8 + (size_t)node * F_OUT + f) = p;
            }
            float es = acc[i].x * av.x + acc[i].y * av.y + acc[i].z * av.z + acc[i].w * av.w;
            float ed = acc[i].x * dv.x + acc[i].y * dv.y + acc[i].z * dv.z + acc[i].w * dv.w;
#pragma unroll
            for (int off = 8; off > 0; off >>= 1) {
                es += __shfl_xor(es, off, 16);
                ed += __shfl_xor(ed, off, 16);
            }
            if ((cg & 15) == 0 && node < NN) {
                esrc[node * 2 + head] = es;
                edst[node * 2 + head] = ed;
            }
        }
    } else {
        float4 bv = *(const float4*)(pb + f);
#pragma unroll
        for (int i = 0; i < 8; ++i) {
            int node = base + g * 8 + i;
            if (node < NN) {
                float4 r = acc[i];
                r.x += bv.x; r.y += bv.y; r.z += bv.z; r.w += bv.w;
                *(float4*)(rout + (size_t)node * F_OUT + f) = r;
            }
        }
    }
}

// ---------------- fused aggregate, F=128 (fp8 h, padded CSR, precomputed w) --
// R8 lesson: NO local arrays (type-punned array fills defeat SROA → LDS
// demotion + bank conflicts). Everything in named int4/float4 scalars.

__global__ __launch_bounds__(256) void aggregate128_kernel(
    const unsigned short* __restrict__ h8s,
    const int* __restrict__ row2_start, const int* __restrict__ row2_deg,
    const int* __restrict__ csr2_src, const float2* __restrict__ csr_w,
    const float* __restrict__ bias, const float* __restrict__ bng,
    const float* __restrict__ bnb, const float* __restrict__ bnm,
    const float* __restrict__ bnv, float* __restrict__ out, int nN)
{
    int w = threadIdx.x >> 6;
    int lane = threadIdx.x & 63;
    int n = blockIdx.x * 4 + w;
    if (n >= nN) return;
    bool hi = lane >= 32;
    int s2 = row2_start[n];
    int dg = row2_deg[n];
    int pc = (dg + 7) & ~7;
    const int4* sp = (const int4*)(csr2_src + s2);
    const float4* wp = (const float4*)(csr_w + s2);
    float s = 0.f, ax = 0.f, ay = 0.f;
    for (int j = 0; j < pc; j += 8) {
        int4 ia = sp[(j >> 2) + 0];
        int4 ib = sp[(j >> 2) + 1];
        float4 wa = wp[(j >> 1) + 0];
        float4 wb = wp[(j >> 1) + 1];
        float4 wc = wp[(j >> 1) + 2];
        float4 wd = wp[(j >> 1) + 3];
        unsigned short v0 = h8s[(size_t)ia.x * 64 + lane];
        unsigned short v1 = h8s[(size_t)ia.y * 64 + lane];
        unsigned short v2 = h8s[(size_t)ia.z * 64 + lane];
        unsigned short v3 = h8s[(size_t)ia.w * 64 + lane];
        unsigned short v4 = h8s[(size_t)ib.x * 64 + lane];
        unsigned short v5 = h8s[(size_t)ib.y * 64 + lane];
        unsigned short v6 = h8s[(size_t)ib.z * 64 + lane];
        unsigned short v7 = h8s[(size_t)ib.w * 64 + lane];
        float g0 = hi ? wa.y : wa.x;
        float g1 = hi ? wa.w : wa.z;
        float g2 = hi ? wb.y : wb.x;
        float g3 = hi ? wb.w : wb.z;
        float g4 = hi ? wc.y : wc.x;
        float g5 = hi ? wc.w : wc.z;
        float g6 = hi ? wd.y : wd.x;
        float g7 = hi ? wd.w : wd.z;
        floatx2 f0 = __builtin_amdgcn_cvt_pk_f32_fp8((int)v0, false);
        floatx2 f1 = __builtin_amdgcn_cvt_pk_f32_fp8((int)v1, false);
        floatx2 f2 = __builtin_amdgcn_cvt_pk_f32_fp8((int)v2, false);
        floatx2 f3 = __builtin_amdgcn_cvt_pk_f32_fp8((int)v3, false);
        floatx2 f4 = __builtin_amdgcn_cvt_pk_f32_fp8((int)v4, false);
        floatx2 f5 = __builtin_amdgcn_cvt_pk_f32_fp8((int)v5, false);
        floatx2 f6 = __builtin_amdgcn_cvt_pk_f32_fp8((int)v6, false);
        floatx2 f7 = __builtin_amdgcn_cvt_pk_f32_fp8((int)v7, false);
        ax = fmaf(g0, f0.x, ax); ay = fmaf(g0, f0.y, ay);
        ax = fmaf(g1, f1.x, ax); ay = fmaf(g1, f1.y, ay);
        ax = fmaf(g2, f2.x, ax); ay = fmaf(g2, f2.y, ay);
        ax = fmaf(g3, f3.x, ax); ay = fmaf(g3, f3.y, ay);
        ax = fmaf(g4, f4.x, ax); ay = fmaf(g4, f4.y, ay);
        ax = fmaf(g5, f5.x, ax); ay = fmaf(g5, f5.y, ay);
        ax = fmaf(g6, f6.x, ax); ay = fmaf(g6, f6.y, ay);
        ax = fmaf(g7, f7.x, ax); ay = fmaf(g7, f7.y, ay);
        s += ((g0 + g1) + (g2 + g3)) + ((g4 + g5) + (g6 + g7));
    }
    float inv = 1.f / (s + 1e-16f);
    int f0i = 2 * lane, f1i = 2 * lane + 1;
    float o0 = bng[f0i] * (ax * inv + bias[f0i] - bnm[f0i]) * rsqrtf(bnv[f0i] + BNEPS) + bnb[f0i];
    float o1 = bng[f1i] * (ay * inv + bias[f1i] - bnm[f1i]) * rsqrtf(bnv[f1i] + BNEPS) + bnb[f1i];
    float2* op = (float2*)(out + (size_t)n * 128) + lane;
    float2 prev = *op;
    prev.x += fmaxf(o0, 0.f);
    prev.y += fmaxf(o1, 0.f);
    *op = prev;
}

// ---------------- fused aggregate, F=64 ---------------------------------------

__global__ __launch_bounds__(256) void aggregate64_kernel(
    const unsigned char* __restrict__ h8,
    const int* __restrict__ row2_start, const int* __restrict__ row2_deg,
    const int* __restrict__ csr2_src, const float2* __restrict__ csr_w,
    const float* __restrict__ bias, const float* __restrict__ bng,
    const float* __restrict__ bnb, const float* __restrict__ bnm,
    const float* __restrict__ bnv, float* __restrict__ out, int nN)
{
    int w = threadIdx.x >> 6;
    int lane = threadIdx.x & 63;
    int n = blockIdx.x * 4 + w;
    if (n >= nN) return;
    bool hi = lane >= 32;
    int s2 = row2_start[n];
    int dg = row2_deg[n];
    int pc = (dg + 7) & ~7;
    const int4* sp = (const int4*)(csr2_src + s2);
    const float4* wp = (const float4*)(csr_w + s2);
    float s = 0.f, acc = 0.f;
    for (int j = 0; j < pc; j += 8) {
        int4 ia = sp[(j >> 2) + 0];
        int4 ib = sp[(j >> 2) + 1];
        float4 wa = wp[(j >> 1) + 0];
        float4 wb = wp[(j >> 1) + 1];
        float4 wc = wp[(j >> 1) + 2];
        float4 wd = wp[(j >> 1) + 3];
        unsigned char v0 = h8[(size_t)ia.x * 64 + lane];
        unsigned char v1 = h8[(size_t)ia.y * 64 + lane];
        unsigned char v2 = h8[(size_t)ia.z * 64 + lane];
        unsigned char v3 = h8[(size_t)ia.w * 64 + lane];
        unsigned char v4 = h8[(size_t)ib.x * 64 + lane];
        unsigned char v5 = h8[(size_t)ib.y * 64 + lane];
        unsigned char v6 = h8[(size_t)ib.z * 64 + lane];
        unsigned char v7 = h8[(size_t)ib.w * 64 + lane];
        float g0 = hi ? wa.y : wa.x;
        float g1 = hi ? wa.w : wa.z;
        float g2 = hi ? wb.y : wb.x;
        float g3 = hi ? wb.w : wb.z;
        float g4 = hi ? wc.y : wc.x;
        float g5 = hi ? wc.w : wc.z;
        float g6 = hi ? wd.y : wd.x;
        float g7 = hi ? wd.w : wd.z;
        acc = fmaf(g0, __builtin_amdgcn_cvt_f32_fp8((int)v0, 0), acc);
        acc = fmaf(g1, __builtin_amdgcn_cvt_f32_fp8((int)v1, 0), acc);
        acc = fmaf(g2, __builtin_amdgcn_cvt_f32_fp8((int)v2, 0), acc);
        acc = fmaf(g3, __builtin_amdgcn_cvt_f32_fp8((int)v3, 0), acc);
        acc = fmaf(g4, __builtin_amdgcn_cvt_f32_fp8((int)v4, 0), acc);
        acc = fmaf(g5, __builtin_amdgcn_cvt_f32_fp8((int)v5, 0), acc);
        acc = fmaf(g6, __builtin_amdgcn_cvt_f32_fp8((int)v6, 0), acc);
        acc = fmaf(g7, __builtin_amdgcn_cvt_f32_fp8((int)v7, 0), acc);
        s += ((g0 + g1) + (g2 + g3)) + ((g4 + g5) + (g6 + g7));
    }
    int f = lane;
    float g = acc / (s + 1e-16f);
    float vv = bng[f] * (g + bias[f] - bnm[f]) * rsqrtf(bnv[f] + BNEPS) + bnb[f];
    out[(size_t)n * 64 + f] = fmaxf(vv, 0.f) + out[(size_t)n * 64 + f];
}

// ---------------- pooling (segment mean over sorted batch) ----------------

__global__ __launch_bounds__(128) void pool_kernel(const float* __restrict__ hfin,
                                                   const int* __restrict__ batch,
                                                   float* __restrict__ pooled) {
    int g = blockIdx.x;
    int f = threadIdx.x;
    int lo = 0, hi = NN;
    while (lo < hi) { int mid = (lo + hi) >> 1; if (batch[mid] < g) lo = mid + 1; else hi = mid; }
    int start = lo;
    hi = NN;
    while (lo < hi) { int mid = (lo + hi) >> 1; if (batch[mid] < g + 1) lo = mid + 1; else hi = mid; }
    int end = lo;
    float acc = 0.f;
    for (int i = start; i < end; ++i) acc += hfin[(size_t)i * 128 + f];
    float cnt = (float)(end - start);
    pooled[g * 128 + f] = acc / fmaxf(cnt, 1.0f);
}

// ---------------- MLP head ----------------

__global__ __launch_bounds__(128) void head_kernel(
    const float* __restrict__ pooled, const float* __restrict__ fw, const float* __restrict__ fb,
    const float* __restrict__ g4, const float* __restrict__ be4,
    const float* __restrict__ m4, const float* __restrict__ v4,
    const float* __restrict__ l1w, const float* __restrict__ l1b,
    const float* __restrict__ l2w, const float* __restrict__ l2b,
    float* __restrict__ out)
{
    __shared__ float p[128];
    __shared__ float z1[32];
    __shared__ float z2[32];
    int g = blockIdx.x, t = threadIdx.x;
    p[t] = pooled[g * 128 + t];
    __syncthreads();
    if (t < 32) {
        float acc = fb[t];
        for (int k = 0; k < 128; ++k) acc += p[k] * fw[k * 32 + t];
        float val = g4[t] * (acc - m4[t]) * rsqrtf(v4[t] + BNEPS) + be4[t];
        z1[t] = fmaxf(val, 0.f);
    }
    __syncthreads();
    if (t < 32) {
        float acc = l1b[t];
        for (int k = 0; k < 32; ++k) acc += z1[k] * l1w[k * 32 + t];
        z2[t] = fmaxf(acc, 0.f);
    }
    __syncthreads();
    if (t < 10) {
        float acc = l2b[t];
        for (int k = 0; k < 32; ++k) acc += z2[k] * l2w[k * 10 + t];
        out[g * 10 + t] = acc;
    }
}

// ---------------- launch ----------------

extern "C" void kernel_launch(void* const* d_in, const int* in_sizes, int n_in,
                              void* d_out, int out_size, void* d_ws, size_t ws_size,
                              hipStream_t stream) {
    const float* x     = (const float*)d_in[0];
    const int*   ei    = (const int*)d_in[1];
    const int*   batch = (const int*)d_in[2];
    const float* w1  = (const float*)d_in[3];
    const float* as1 = (const float*)d_in[4];
    const float* ad1 = (const float*)d_in[5];
    const float* b1  = (const float*)d_in[6];
    const float* g1  = (const float*)d_in[7];
    const float* be1 = (const float*)d_in[8];
    const float* m1  = (const float*)d_in[9];
    const float* v1  = (const float*)d_in[10];
    const float* p1w = (const float*)d_in[11];
    const float* p1b = (const float*)d_in[12];
    const float* w2  = (const float*)d_in[13];
    const float* as2 = (const float*)d_in[14];
    const float* ad2 = (const float*)d_in[15];
    const float* b2  = (const float*)d_in[16];
    const float* g2  = (const float*)d_in[17];
    const float* be2 = (const float*)d_in[18];
    const float* m2  = (const float*)d_in[19];
    const float* v2  = (const float*)d_in[20];
    const float* p2w = (const float*)d_in[21];
    const float* p2b = (const float*)d_in[22];
    const float* w3  = (const float*)d_in[23];
    const float* as3 = (const float*)d_in[24];
    const float* ad3 = (const float*)d_in[25];
    const float* b3  = (const float*)d_in[26];
    const float* g3  = (const float*)d_in[27];
    const float* be3 = (const float*)d_in[28];
    const float* m3  = (const float*)d_in[29];
    const float* v3  = (const float*)d_in[30];
    const float* p3w = (const float*)d_in[31];
    const float* p3b = (const float*)d_in[32];
    const float* fw  = (const float*)d_in[33];
    const float* fb  = (const float*)d_in[34];
    const float* g4  = (const float*)d_in[35];
    const float* be4 = (const float*)d_in[36];
    const float* m4  = (const float*)d_in[37];
    const float* v4  = (const float*)d_in[38];
    const float* l1w = (const float*)d_in[39];
    const float* l1b = (const float*)d_in[40];
    const float* l2w = (const float*)d_in[41];
    const float* l2b = (const float*)d_in[42];

    char* ws = (char*)d_ws;
    size_t off = 0;
    auto alloc = [&](size_t bytes) -> char* {
        char* p = ws + off;
        off += (bytes + 255) & ~(size_t)255;
        return p;
    };
    int*    bucket_cnt  = (int*)alloc((NBK) * sizeof(int));
    int*    bucket_base = (int*)alloc((NBK + 1) * sizeof(int));
    int*    gcursor     = (int*)alloc((NBK) * sizeof(int));
    int*    part        = (int*)alloc((size_t)ETOT * sizeof(int));
    int*    row2_start  = (int*)alloc(NN * sizeof(int));
    int*    row2_deg    = (int*)alloc(NN * sizeof(int));
    int*    csr2_src    = (int*)alloc((size_t)PADTOT * sizeof(int));
    float2* csr_w       = (float2*)alloc((size_t)PADTOT * sizeof(float2));
    unsigned char* h8   = (unsigned char*)alloc((size_t)NN * 128);
    float*  bufB        = (float*)alloc((size_t)NN * 128 * sizeof(float));
    float*  bufC        = (float*)alloc((size_t)NN * 128 * sizeof(float));
    float*  esrc        = (float*)alloc((size_t)NN * 2 * sizeof(float));
    float*  edst        = (float*)alloc((size_t)NN * 2 * sizeof(float));
    float*  pooled      = (float*)alloc((size_t)GG * 128 * sizeof(float));

    // ---- CSR build (bucketed partition, padded layout) ----
    hipMemsetAsync(bucket_cnt, 0, NBK * sizeof(int), stream);
    bucket_count_kernel<<<(ETOT + 8191) / 8192, 256, 0, stream>>>(ei, bucket_cnt);
    bucket_scan_kernel<<<1, 512, 0, stream>>>(bucket_cnt, bucket_base, gcursor);
    partition_kernel<<<(ETOT + 4095) / 4096, 256, 0, stream>>>(ei, gcursor, part);
    csr_build_kernel<<<NBK, 256, 0, stream>>>(part, bucket_base, row2_start, row2_deg, csr2_src);

    // ---- layer 1: x[N,5] -> bufB[N,64] ----
    feat1_kernel<<<(NN + 3) / 4, 256, 0, stream>>>(
        x, w1, p1w, p1b, as1, ad1, h8, esrc, edst, bufB, NN);
    edgew_kernel<<<(NN + 3) / 4, 256, 0, stream>>>(
        csr2_src, row2_start, row2_deg, (const float2*)esrc, (const float2*)edst, csr_w, NN);
    aggregate64_kernel<<<(NN + 3) / 4, 256, 0, stream>>>(
        h8, row2_start, row2_deg, csr2_src, csr_w,
        b1, g1, be1, m1, v1, bufB, NN);

    // ---- layer 2: bufB[N,64] -> bufC[N,128] ----
    tiled_feat_kernel<64><<<(NN + 31) / 32, 256, 0, stream>>>(
        bufB, w2, p2w, p2b, as2, ad2, h8, esrc, edst, bufC);
    edgew_kernel<<<(NN + 3) / 4, 256, 0, stream>>>(
        csr2_src, row2_start, row2_deg, (const float2*)esrc, (const float2*)edst, csr_w, NN);
    aggregate128_kernel<<<(NN + 3) / 4, 256, 0, stream>>>(
        (const unsigned short*)h8, row2_start, row2_deg, csr2_src, csr_w,
        b2, g2, be2, m2, v2, bufC, NN);

    // ---- layer 3: bufC[N,128] -> bufB[N,128] ----
    tiled_feat_kernel<128><<<(NN + 31) / 32, 256, 0, stream>>>(
        bufC, w3, p3w, p3b, as3, ad3, h8, esrc, edst, bufB);
    edgew_kernel<<<(NN + 3) / 4, 256, 0, stream>>>(
        csr2_src, row2_start, row2_deg, (const float2*)esrc, (const float2*)edst, csr_w, NN);
    aggregate128_kernel<<<(NN + 3) / 4, 256, 0, stream>>>(
        (const unsigned short*)h8, row2_start, row2_deg, csr2_src, csr_w,
        b3, g3, be3, m3, v3, bufB, NN);

    // ---- pool + head ----
    pool_kernel<<<GG, 128, 0, stream>>>(bufB, batch, pooled);
    head_kernel<<<GG, 128, 0, stream>>>(pooled, fw, fb, g4, be4, m4, v4,
                                        l1w, l1b, l2w, l2b, (float*)d_out);
}

// Round 10
// 688.709 us; speedup vs baseline: 1.6322x; 1.1507x over previous
//
#include <hip/hip_runtime.h>
#include <hip/hip_bf16.h>
#include <hip/hip_fp16.h>

#define NN   100000
#define EE   1600000
#define ETOT (EE + NN)
#define GG   256
#define BNEPS 1e-5f
#define NBK  391          // buckets of 256 nodes: (NN+255)/256
#define PADTOT (ETOT + NBK * 2048 + 64)
#define PSPLIT 16

typedef float floatx2 __attribute__((ext_vector_type(2)));

// ---------------- CSR build: bucketed partition (single-writer cache lines) --

__global__ __launch_bounds__(256) void bucket_count_kernel(
    const int* __restrict__ ei, int* __restrict__ bucket_cnt)
{
    __shared__ int cnt[NBK];
    for (int i = threadIdx.x; i < NBK; i += 256) cnt[i] = 0;
    __syncthreads();
    int base = blockIdx.x * 8192;
    for (int k = threadIdx.x; k < 8192; k += 256) {
        int e = base + k;
        if (e < ETOT) {
            int dst = (e < EE) ? ei[EE + e] : (e - EE);
            atomicAdd(&cnt[dst >> 8], 1);
        }
    }
    __syncthreads();
    for (int i = threadIdx.x; i < NBK; i += 256)
        if (cnt[i]) atomicAdd(&bucket_cnt[i], cnt[i]);
}

__global__ __launch_bounds__(512) void bucket_scan_kernel(
    const int* __restrict__ bucket_cnt, int* __restrict__ bucket_base,
    int* __restrict__ gcursor)
{
    __shared__ int s[512];
    int t = threadIdx.x;
    int v = (t < NBK) ? bucket_cnt[t] : 0;
    s[t] = v;
    __syncthreads();
    int x = v;
    for (int o = 1; o < 512; o <<= 1) {
        int y = (t >= o) ? s[t - o] : 0;
        __syncthreads();
        x += y;
        s[t] = x;
        __syncthreads();
    }
    if (t < NBK) { bucket_base[t] = x - v; gcursor[t] = x - v; }
    if (t == 0) bucket_base[NBK] = ETOT;
}

__global__ __launch_bounds__(256) void partition_kernel(
    const int* __restrict__ ei, int* __restrict__ gcursor, int* __restrict__ part)
{
    __shared__ int cnt[NBK];
    __shared__ int basel[NBK];
    for (int i = threadIdx.x; i < NBK; i += 256) cnt[i] = 0;
    __syncthreads();
    int base = blockIdx.x * 4096;
    for (int k = threadIdx.x; k < 4096; k += 256) {
        int e = base + k;
        if (e < ETOT) {
            int dst = (e < EE) ? ei[EE + e] : (e - EE);
            atomicAdd(&cnt[dst >> 8], 1);
        }
    }
    __syncthreads();
    for (int i = threadIdx.x; i < NBK; i += 256) {
        int c = cnt[i];
        basel[i] = c ? atomicAdd(&gcursor[i], c) : 0;
        cnt[i] = 0;   // reuse as intra-block cursor
    }
    __syncthreads();
    for (int k = threadIdx.x; k < 4096; k += 256) {
        int e = base + k;
        if (e < ETOT) {
            int src, dst;
            if (e < EE) { src = ei[e]; dst = ei[EE + e]; }
            else        { src = e - EE; dst = e - EE; }
            int b = dst >> 8;
            int slot = atomicAdd(&cnt[b], 1);
            part[basel[b] + slot] = src | ((dst & 255) << 17);
        }
    }
}

// Padded CSR: per-node segments rounded up to 8 entries (pad src = 0),
// 8-aligned starts → aggregate loop needs no masking and uses int4 loads.
__global__ __launch_bounds__(256) void csr_build_kernel(
    const int* __restrict__ part, const int* __restrict__ bucket_base,
    int* __restrict__ row2_start, int* __restrict__ row2_deg,
    int* __restrict__ csr2_src)
{
    __shared__ int degs[256];
    __shared__ int sc[256];
    __shared__ int cur[256];
    int b = blockIdx.x;
    int t = threadIdx.x;
    int beg = bucket_base[b], end = bucket_base[b + 1];
    int pbase = ((beg + 7) & ~7) + 2048 * b;
    degs[t] = 0;
    __syncthreads();
    for (int j = beg + t; j < end; j += 256)
        atomicAdd(&degs[(part[j] >> 17) & 255], 1);
    __syncthreads();
    int dg = degs[t];
    int pdeg = (dg + 7) & ~7;
    sc[t] = pdeg;
    __syncthreads();
    int x = pdeg;
    for (int o = 1; o < 256; o <<= 1) {
        int y = (t >= o) ? sc[t - o] : 0;
        __syncthreads();
        x += y;
        sc[t] = x;
        __syncthreads();
    }
    int start2 = pbase + (x - pdeg);
    int node = b * 256 + t;
    if (node < NN) { row2_start[node] = start2; row2_deg[node] = dg; }
    cur[t] = start2;
    __syncthreads();
    for (int j = beg + t; j < end; j += 256) {
        int pv = part[j];
        int pos = atomicAdd(&cur[(pv >> 17) & 255], 1);
        csr2_src[pos] = pv & 0x1FFFF;
    }
    for (int k = dg; k < pdeg; ++k) csr2_src[start2 + k] = 0;
}

// ---------------- per-layer edge softmax weights (both heads, fp32) ----------

__global__ __launch_bounds__(256) void edgew_kernel(
    const int* __restrict__ csr2_src, const int* __restrict__ row2_start,
    const int* __restrict__ row2_deg,
    const float2* __restrict__ esrc, const float2* __restrict__ edst,
    float2* __restrict__ csr_w, int nN)
{
    int n = blockIdx.x * 4 + (threadIdx.x >> 6);
    int lane = threadIdx.x & 63;
    if (n >= nN) return;
    float2 ed = edst[n];
    int s2 = row2_start[n];
    int dg = row2_deg[n];
    int pc = (dg + 7) & ~7;
    for (int j = lane; j < pc; j += 64) {
        float2 w = make_float2(0.f, 0.f);
        if (j < dg) {
            int i = csr2_src[s2 + j];
            float2 es = esrc[i];
            float a0 = es.x + ed.x; a0 = (a0 > 0.f) ? a0 : 0.2f * a0;
            float a1 = es.y + ed.y; a1 = (a1 > 0.f) ? a1 : 0.2f * a1;
            w.x = __expf(a0);
            w.y = __expf(a1);
        }
        csr_w[s2 + j] = w;
    }
}

// ---------------- layer-1 feature transform (K=5); h stored fp8 e4m3 ---------

__global__ __launch_bounds__(256) void feat1_kernel(
    const float* __restrict__ xin, const float* __restrict__ W,
    const float* __restrict__ pw, const float* __restrict__ pb,
    const float* __restrict__ a_src, const float* __restrict__ a_dst,
    unsigned char* __restrict__ h8, float* __restrict__ esrc, float* __restrict__ edst,
    float* __restrict__ rout, int nN)
{
    constexpr int F_IN = 5, F_OUT = 64;
    int t = threadIdx.x;
    int n = blockIdx.x * 4 + t / F_OUT;
    int f = t % F_OUT;
    if (n >= nN) return;
    float acc = 0.f, racc = 0.f;
#pragma unroll
    for (int k = 0; k < F_IN; ++k) {
        float xv = xin[n * F_IN + k];
        acc  += xv * W[k * F_OUT + f];
        racc += xv * pw[k * F_OUT + f];
    }
    float other = __shfl_xor(acc, 1, 64);
    if ((f & 1) == 0) {
        int p = __builtin_amdgcn_cvt_pk_fp8_f32(acc, other, 0, false);
        *(unsigned short*)(h8 + (size_t)n * F_OUT + f) = (unsigned short)(p & 0xFFFF);
    }
    rout[(size_t)n * F_OUT + f] = racc + pb[f];
    float es = acc * a_src[f];
    float ed = acc * a_dst[f];
#pragma unroll
    for (int off = 16; off > 0; off >>= 1) {
        es += __shfl_xor(es, off, 32);
        ed += __shfl_xor(ed, off, 32);
    }
    if ((t & 31) == 0) {
        int head = (f >> 5) & 1;
        esrc[n * 2 + head] = es;
        edst[n * 2 + head] = ed;
    }
}

// ---------------- register-tiled feature transform (layers 2,3; F_OUT=128) ----

template<int F_IN>
__global__ __launch_bounds__(256, 4) void tiled_feat_kernel(
    const float* __restrict__ xin, const float* __restrict__ W,
    const float* __restrict__ pw, const float* __restrict__ pb,
    const float* __restrict__ a_src, const float* __restrict__ a_dst,
    unsigned char* __restrict__ h8, float* __restrict__ esrc, float* __restrict__ edst,
    float* __restrict__ rout)
{
    constexpr int F_OUT = 128;
    constexpr int TILE_M = 32;
    constexpr int K4 = F_IN / 4;
    __shared__ float4 xs4[TILE_M * K4];

    const int tid = threadIdx.x;
    const int cg  = tid & 63;
    const int g   = tid >> 6;
    const int base = blockIdx.x * TILE_M;

    constexpr int NV = TILE_M * K4;
    const float4* xg4 = (const float4*)xin;
    const int maxv = NN * K4 - 1;
#pragma unroll
    for (int i = tid; i < NV; i += 256) {
        int gi = base * K4 + i;
        xs4[i] = xg4[gi <= maxv ? gi : maxv];
    }
    __syncthreads();

    const int col4 = cg * 4;
    const bool isW = (col4 < F_OUT);
    const float* wbase = isW ? W : pw;
    const int f = isW ? col4 : (col4 - F_OUT);

    float4 acc[8];
#pragma unroll
    for (int i = 0; i < 8; ++i) acc[i] = make_float4(0.f, 0.f, 0.f, 0.f);

    for (int k0 = 0; k0 < F_IN; k0 += 4) {
        float4 w0 = *(const float4*)(wbase + (size_t)(k0 + 0) * F_OUT + f);
        float4 w1 = *(const float4*)(wbase + (size_t)(k0 + 1) * F_OUT + f);
        float4 w2 = *(const float4*)(wbase + (size_t)(k0 + 2) * F_OUT + f);
        float4 w3 = *(const float4*)(wbase + (size_t)(k0 + 3) * F_OUT + f);
#pragma unroll
        for (int i = 0; i < 8; ++i) {
            float4 xv = xs4[(g * 8 + i) * K4 + (k0 >> 2)];
            acc[i].x = fmaf(xv.x, w0.x, acc[i].x);
            acc[i].y = fmaf(xv.x, w0.y, acc[i].y);
            acc[i].z = fmaf(xv.x, w0.z, acc[i].z);
            acc[i].w = fmaf(xv.x, w0.w, acc[i].w);
            acc[i].x = fmaf(xv.y, w1.x, acc[i].x);
            acc[i].y = fmaf(xv.y, w1.y, acc[i].y);
            acc[i].z = fmaf(xv.y, w1.z, acc[i].z);
            acc[i].w = fmaf(xv.y, w1.w, acc[i].w);
            acc[i].x = fmaf(xv.z, w2.x, acc[i].x);
            acc[i].y = fmaf(xv.z, w2.y, acc[i].y);
            acc[i].z = fmaf(xv.z, w2.z, acc[i].z);
            acc[i].w = fmaf(xv.z, w2.w, acc[i].w);
            acc[i].x = fmaf(xv.w, w3.x, acc[i].x);
            acc[i].y = fmaf(xv.w, w3.y, acc[i].y);
            acc[i].z = fmaf(xv.w, w3.z, acc[i].z);
            acc[i].w = fmaf(xv.w, w3.w, acc[i].w);
        }
    }

    if (isW) {
        float4 av = *(const float4*)(a_src + f);
        float4 dv = *(const float4*)(a_dst + f);
        int head = cg >> 4;
#pragma unroll
        for (int i = 0; i < 8; ++i) {
            int node = base + g * 8 + i;
            if (node < NN) {
                int p = __builtin_amdgcn_cvt_pk_fp8_f32(acc[i].x, acc[i].y, 0, false);
                p = __builtin_amdgcn_cvt_pk_fp8_f32(acc[i].z, acc[i].w, p, true);
                *(int*)(h8 + (size_t)node * F_OUT + f) = p;
            }
            float es = acc[i].x * av.x + acc[i].y * av.y + acc[i].z * av.z + acc[i].w * av.w;
            float ed = acc[i].x * dv.x + acc[i].y * dv.y + acc[i].z * dv.z + acc[i].w * dv.w;
#pragma unroll
            for (int off = 8; off > 0; off >>= 1) {
                es += __shfl_xor(es, off, 16);
                ed += __shfl_xor(ed, off, 16);
            }
            if ((cg & 15) == 0 && node < NN) {
                esrc[node * 2 + head] = es;
                edst[node * 2 + head] = ed;
            }
        }
    } else {
        float4 bv = *(const float4*)(pb + f);
#pragma unroll
        for (int i = 0; i < 8; ++i) {
            int node = base + g * 8 + i;
            if (node < NN) {
                float4 r = acc[i];
                r.x += bv.x; r.y += bv.y; r.z += bv.z; r.w += bv.w;
                *(float4*)(rout + (size_t)node * F_OUT + f) = r;
            }
        }
    }
}

// ---------------- fused aggregate, F=128 (fp8 h, padded CSR, precomputed w) --
// No local arrays (R8 lesson: SROA failure → LDS demotion). Named scalars only.

__global__ __launch_bounds__(256) void aggregate128_kernel(
    const unsigned short* __restrict__ h8s,
    const int* __restrict__ row2_start, const int* __restrict__ row2_deg,
    const int* __restrict__ csr2_src, const float2* __restrict__ csr_w,
    const float* __restrict__ bias, const float* __restrict__ bng,
    const float* __restrict__ bnb, const float* __restrict__ bnm,
    const float* __restrict__ bnv, float* __restrict__ out, int nN)
{
    int w = threadIdx.x >> 6;
    int lane = threadIdx.x & 63;
    int n = blockIdx.x * 4 + w;
    if (n >= nN) return;
    bool hi = lane >= 32;
    int s2 = row2_start[n];
    int dg = row2_deg[n];
    int pc = (dg + 7) & ~7;
    const int4* sp = (const int4*)(csr2_src + s2);
    const float4* wp = (const float4*)(csr_w + s2);
    float s = 0.f, ax = 0.f, ay = 0.f;
    for (int j = 0; j < pc; j += 8) {
        int4 ia = sp[(j >> 2) + 0];
        int4 ib = sp[(j >> 2) + 1];
        float4 wa = wp[(j >> 1) + 0];
        float4 wb = wp[(j >> 1) + 1];
        float4 wc = wp[(j >> 1) + 2];
        float4 wd = wp[(j >> 1) + 3];
        unsigned short v0 = h8s[(size_t)ia.x * 64 + lane];
        unsigned short v1 = h8s[(size_t)ia.y * 64 + lane];
        unsigned short v2 = h8s[(size_t)ia.z * 64 + lane];
        unsigned short v3 = h8s[(size_t)ia.w * 64 + lane];
        unsigned short v4 = h8s[(size_t)ib.x * 64 + lane];
        unsigned short v5 = h8s[(size_t)ib.y * 64 + lane];
        unsigned short v6 = h8s[(size_t)ib.z * 64 + lane];
        unsigned short v7 = h8s[(size_t)ib.w * 64 + lane];
        float g0 = hi ? wa.y : wa.x;
        float g1 = hi ? wa.w : wa.z;
        float g2 = hi ? wb.y : wb.x;
        float g3 = hi ? wb.w : wb.z;
        float g4 = hi ? wc.y : wc.x;
        float g5 = hi ? wc.w : wc.z;
        float g6 = hi ? wd.y : wd.x;
        float g7 = hi ? wd.w : wd.z;
        floatx2 f0 = __builtin_amdgcn_cvt_pk_f32_fp8((int)v0, false);
        floatx2 f1 = __builtin_amdgcn_cvt_pk_f32_fp8((int)v1, false);
        floatx2 f2 = __builtin_amdgcn_cvt_pk_f32_fp8((int)v2, false);
        floatx2 f3 = __builtin_amdgcn_cvt_pk_f32_fp8((int)v3, false);
        floatx2 f4 = __builtin_amdgcn_cvt_pk_f32_fp8((int)v4, false);
        floatx2 f5 = __builtin_amdgcn_cvt_pk_f32_fp8((int)v5, false);
        floatx2 f6 = __builtin_amdgcn_cvt_pk_f32_fp8((int)v6, false);
        floatx2 f7 = __builtin_amdgcn_cvt_pk_f32_fp8((int)v7, false);
        ax = fmaf(g0, f0.x, ax); ay = fmaf(g0, f0.y, ay);
        ax = fmaf(g1, f1.x, ax); ay = fmaf(g1, f1.y, ay);
        ax = fmaf(g2, f2.x, ax); ay = fmaf(g2, f2.y, ay);
        ax = fmaf(g3, f3.x, ax); ay = fmaf(g3, f3.y, ay);
        ax = fmaf(g4, f4.x, ax); ay = fmaf(g4, f4.y, ay);
        ax = fmaf(g5, f5.x, ax); ay = fmaf(g5, f5.y, ay);
        ax = fmaf(g6, f6.x, ax); ay = fmaf(g6, f6.y, ay);
        ax = fmaf(g7, f7.x, ax); ay = fmaf(g7, f7.y, ay);
        s += ((g0 + g1) + (g2 + g3)) + ((g4 + g5) + (g6 + g7));
    }
    float inv = 1.f / (s + 1e-16f);
    int f0i = 2 * lane, f1i = 2 * lane + 1;
    float o0 = bng[f0i] * (ax * inv + bias[f0i] - bnm[f0i]) * rsqrtf(bnv[f0i] + BNEPS) + bnb[f0i];
    float o1 = bng[f1i] * (ay * inv + bias[f1i] - bnm[f1i]) * rsqrtf(bnv[f1i] + BNEPS) + bnb[f1i];
    float2* op = (float2*)(out + (size_t)n * 128) + lane;
    float2 prev = *op;
    prev.x += fmaxf(o0, 0.f);
    prev.y += fmaxf(o1, 0.f);
    *op = prev;
}

// ---------------- fused aggregate, F=64 ---------------------------------------

__global__ __launch_bounds__(256) void aggregate64_kernel(
    const unsigned char* __restrict__ h8,
    const int* __restrict__ row2_start, const int* __restrict__ row2_deg,
    const int* __restrict__ csr2_src, const float2* __restrict__ csr_w,
    const float* __restrict__ bias, const float* __restrict__ bng,
    const float* __restrict__ bnb, const float* __restrict__ bnm,
    const float* __restrict__ bnv, float* __restrict__ out, int nN)
{
    int w = threadIdx.x >> 6;
    int lane = threadIdx.x & 63;
    int n = blockIdx.x * 4 + w;
    if (n >= nN) return;
    bool hi = lane >= 32;
    int s2 = row2_start[n];
    int dg = row2_deg[n];
    int pc = (dg + 7) & ~7;
    const int4* sp = (const int4*)(csr2_src + s2);
    const float4* wp = (const float4*)(csr_w + s2);
    float s = 0.f, acc = 0.f;
    for (int j = 0; j < pc; j += 8) {
        int4 ia = sp[(j >> 2) + 0];
        int4 ib = sp[(j >> 2) + 1];
        float4 wa = wp[(j >> 1) + 0];
        float4 wb = wp[(j >> 1) + 1];
        float4 wc = wp[(j >> 1) + 2];
        float4 wd = wp[(j >> 1) + 3];
        unsigned char v0 = h8[(size_t)ia.x * 64 + lane];
        unsigned char v1 = h8[(size_t)ia.y * 64 + lane];
        unsigned char v2 = h8[(size_t)ia.z * 64 + lane];
        unsigned char v3 = h8[(size_t)ia.w * 64 + lane];
        unsigned char v4 = h8[(size_t)ib.x * 64 + lane];
        unsigned char v5 = h8[(size_t)ib.y * 64 + lane];
        unsigned char v6 = h8[(size_t)ib.z * 64 + lane];
        unsigned char v7 = h8[(size_t)ib.w * 64 + lane];
        float g0 = hi ? wa.y : wa.x;
        float g1 = hi ? wa.w : wa.z;
        float g2 = hi ? wb.y : wb.x;
        float g3 = hi ? wb.w : wb.z;
        float g4 = hi ? wc.y : wc.x;
        float g5 = hi ? wc.w : wc.z;
        float g6 = hi ? wd.y : wd.x;
        float g7 = hi ? wd.w : wd.z;
        acc = fmaf(g0, __builtin_amdgcn_cvt_f32_fp8((int)v0, 0), acc);
        acc = fmaf(g1, __builtin_amdgcn_cvt_f32_fp8((int)v1, 0), acc);
        acc = fmaf(g2, __builtin_amdgcn_cvt_f32_fp8((int)v2, 0), acc);
        acc = fmaf(g3, __builtin_amdgcn_cvt_f32_fp8((int)v3, 0), acc);
        acc = fmaf(g4, __builtin_amdgcn_cvt_f32_fp8((int)v4, 0), acc);
        acc = fmaf(g5, __builtin_amdgcn_cvt_f32_fp8((int)v5, 0), acc);
        acc = fmaf(g6, __builtin_amdgcn_cvt_f32_fp8((int)v6, 0), acc);
        acc = fmaf(g7, __builtin_amdgcn_cvt_f32_fp8((int)v7, 0), acc);
        s += ((g0 + g1) + (g2 + g3)) + ((g4 + g5) + (g6 + g7));
    }
    int f = lane;
    float g = acc / (s + 1e-16f);
    float vv = bng[f] * (g + bias[f] - bnm[f]) * rsqrtf(bnv[f] + BNEPS) + bnb[f];
    out[(size_t)n * 64 + f] = fmaxf(vv, 0.f) + out[(size_t)n * 64 + f];
}

// ---------------- pooling, two-phase (R9: one block/graph = 4.9% occupancy) --
// Phase 1: GG×PSPLIT blocks, each sums a contiguous slice of its graph's rows.

__global__ __launch_bounds__(128) void pool_partial_kernel(
    const float* __restrict__ hfin, const int* __restrict__ batch,
    float* __restrict__ ppart)
{
    int g = blockIdx.x / PSPLIT;
    int p = blockIdx.x % PSPLIT;
    int f = threadIdx.x;
    int lo = 0, hi = NN;
    while (lo < hi) { int mid = (lo + hi) >> 1; if (batch[mid] < g) lo = mid + 1; else hi = mid; }
    int start = lo;
    hi = NN;
    while (lo < hi) { int mid = (lo + hi) >> 1; if (batch[mid] < g + 1) lo = mid + 1; else hi = mid; }
    int end = lo;
    int len = end - start;
    int chunk = (len + PSPLIT - 1) / PSPLIT;
    int i0 = start + p * chunk;
    int i1 = i0 + chunk; if (i1 > end) i1 = end;
    float acc = 0.f;
    for (int i = i0; i < i1; ++i) acc += hfin[(size_t)i * 128 + f];
    ppart[((size_t)g * PSPLIT + p) * 128 + f] = acc;
}

// ---------------- MLP head (folds partial-sum reduce + mean) -----------------

__global__ __launch_bounds__(128) void head_kernel(
    const float* __restrict__ ppart, const int* __restrict__ batch,
    const float* __restrict__ fw, const float* __restrict__ fb,
    const float* __restrict__ g4, const float* __restrict__ be4,
    const float* __restrict__ m4, const float* __restrict__ v4,
    const float* __restrict__ l1w, const float* __restrict__ l1b,
    const float* __restrict__ l2w, const float* __restrict__ l2b,
    float* __restrict__ out)
{
    __shared__ float p[128];
    __shared__ float z1[32];
    __shared__ float z2[32];
    int g = blockIdx.x, t = threadIdx.x;
    int lo = 0, hi = NN;
    while (lo < hi) { int mid = (lo + hi) >> 1; if (batch[mid] < g) lo = mid + 1; else hi = mid; }
    int start = lo;
    hi = NN;
    while (lo < hi) { int mid = (lo + hi) >> 1; if (batch[mid] < g + 1) lo = mid + 1; else hi = mid; }
    float cnt = (float)(lo - start);
    float acc = 0.f;
#pragma unroll
    for (int q = 0; q < PSPLIT; ++q)
        acc += ppart[((size_t)g * PSPLIT + q) * 128 + t];
    p[t] = acc / fmaxf(cnt, 1.0f);
    __syncthreads();
    if (t < 32) {
        float a = fb[t];
        for (int k = 0; k < 128; ++k) a += p[k] * fw[k * 32 + t];
        float val = g4[t] * (a - m4[t]) * rsqrtf(v4[t] + BNEPS) + be4[t];
        z1[t] = fmaxf(val, 0.f);
    }
    __syncthreads();
    if (t < 32) {
        float a = l1b[t];
        for (int k = 0; k < 32; ++k) a += z1[k] * l1w[k * 32 + t];
        z2[t] = fmaxf(a, 0.f);
    }
    __syncthreads();
    if (t < 10) {
        float a = l2b[t];
        for (int k = 0; k < 32; ++k) a += z2[k] * l2w[k * 10 + t];
        out[g * 10 + t] = a;
    }
}

// ---------------- launch ----------------

extern "C" void kernel_launch(void* const* d_in, const int* in_sizes, int n_in,
                              void* d_out, int out_size, void* d_ws, size_t ws_size,
                              hipStream_t stream) {
    const float* x     = (const float*)d_in[0];
    const int*   ei    = (const int*)d_in[1];
    const int*   batch = (const int*)d_in[2];
    const float* w1  = (const float*)d_in[3];
    const float* as1 = (const float*)d_in[4];
    const float* ad1 = (const float*)d_in[5];
    const float* b1  = (const float*)d_in[6];
    const float* g1  = (const float*)d_in[7];
    const float* be1 = (const float*)d_in[8];
    const float* m1  = (const float*)d_in[9];
    const float* v1  = (const float*)d_in[10];
    const float* p1w = (const float*)d_in[11];
    const float* p1b = (const float*)d_in[12];
    const float* w2  = (const float*)d_in[13];
    const float* as2 = (const float*)d_in[14];
    const float* ad2 = (const float*)d_in[15];
    const float* b2  = (const float*)d_in[16];
    const float* g2  = (const float*)d_in[17];
    const float* be2 = (const float*)d_in[18];
    const float* m2  = (const float*)d_in[19];
    const float* v2  = (const float*)d_in[20];
    const float* p2w = (const float*)d_in[21];
    const float* p2b = (const float*)d_in[22];
    const float* w3  = (const float*)d_in[23];
    const float* as3 = (const float*)d_in[24];
    const float* ad3 = (const float*)d_in[25];
    const float* b3  = (const float*)d_in[26];
    const float* g3  = (const float*)d_in[27];
    const float* be3 = (const float*)d_in[28];
    const float* m3  = (const float*)d_in[29];
    const float* v3  = (const float*)d_in[30];
    const float* p3w = (const float*)d_in[31];
    const float* p3b = (const float*)d_in[32];
    const float* fw  = (const float*)d_in[33];
    const float* fb  = (const float*)d_in[34];
    const float* g4  = (const float*)d_in[35];
    const float* be4 = (const float*)d_in[36];
    const float* m4  = (const float*)d_in[37];
    const float* v4  = (const float*)d_in[38];
    const float* l1w = (const float*)d_in[39];
    const float* l1b = (const float*)d_in[40];
    const float* l2w = (const float*)d_in[41];
    const float* l2b = (const float*)d_in[42];

    char* ws = (char*)d_ws;
    size_t off = 0;
    auto alloc = [&](size_t bytes) -> char* {
        char* p = ws + off;
        off += (bytes + 255) & ~(size_t)255;
        return p;
    };
    int*    bucket_cnt  = (int*)alloc((NBK) * sizeof(int));
    int*    bucket_base = (int*)alloc((NBK + 1) * sizeof(int));
    int*    gcursor     = (int*)alloc((NBK) * sizeof(int));
    int*    part        = (int*)alloc((size_t)ETOT * sizeof(int));
    int*    row2_start  = (int*)alloc(NN * sizeof(int));
    int*    row2_deg    = (int*)alloc(NN * sizeof(int));
    int*    csr2_src    = (int*)alloc((size_t)PADTOT * sizeof(int));
    float2* csr_w       = (float2*)alloc((size_t)PADTOT * sizeof(float2));
    unsigned char* h8   = (unsigned char*)alloc((size_t)NN * 128);
    float*  bufB        = (float*)alloc((size_t)NN * 128 * sizeof(float));
    float*  bufC        = (float*)alloc((size_t)NN * 128 * sizeof(float));
    float*  esrc        = (float*)alloc((size_t)NN * 2 * sizeof(float));
    float*  edst        = (float*)alloc((size_t)NN * 2 * sizeof(float));
    float*  ppart       = (float*)alloc((size_t)GG * PSPLIT * 128 * sizeof(float));

    // ---- CSR build (bucketed partition, padded layout) ----
    hipMemsetAsync(bucket_cnt, 0, NBK * sizeof(int), stream);
    bucket_count_kernel<<<(ETOT + 8191) / 8192, 256, 0, stream>>>(ei, bucket_cnt);
    bucket_scan_kernel<<<1, 512, 0, stream>>>(bucket_cnt, bucket_base, gcursor);
    partition_kernel<<<(ETOT + 4095) / 4096, 256, 0, stream>>>(ei, gcursor, part);
    csr_build_kernel<<<NBK, 256, 0, stream>>>(part, bucket_base, row2_start, row2_deg, csr2_src);

    // ---- layer 1: x[N,5] -> bufB[N,64] ----
    feat1_kernel<<<(NN + 3) / 4, 256, 0, stream>>>(
        x, w1, p1w, p1b, as1, ad1, h8, esrc, edst, bufB, NN);
    edgew_kernel<<<(NN + 3) / 4, 256, 0, stream>>>(
        csr2_src, row2_start, row2_deg, (const float2*)esrc, (const float2*)edst, csr_w, NN);
    aggregate64_kernel<<<(NN + 3) / 4, 256, 0, stream>>>(
        h8, row2_start, row2_deg, csr2_src, csr_w,
        b1, g1, be1, m1, v1, bufB, NN);

    // ---- layer 2: bufB[N,64] -> bufC[N,128] ----
    tiled_feat_kernel<64><<<(NN + 31) / 32, 256, 0, stream>>>(
        bufB, w2, p2w, p2b, as2, ad2, h8, esrc, edst, bufC);
    edgew_kernel<<<(NN + 3) / 4, 256, 0, stream>>>(
        csr2_src, row2_start, row2_deg, (const float2*)esrc, (const float2*)edst, csr_w, NN);
    aggregate128_kernel<<<(NN + 3) / 4, 256, 0, stream>>>(
        (const unsigned short*)h8, row2_start, row2_deg, csr2_src, csr_w,
        b2, g2, be2, m2, v2, bufC, NN);

    // ---- layer 3: bufC[N,128] -> bufB[N,128] ----
    tiled_feat_kernel<128><<<(NN + 31) / 32, 256, 0, stream>>>(
        bufC, w3, p3w, p3b, as3, ad3, h8, esrc, edst, bufB);
    edgew_kernel<<<(NN + 3) / 4, 256, 0, stream>>>(
        csr2_src, row2_start, row2_deg, (const float2*)esrc, (const float2*)edst, csr_w, NN);
    aggregate128_kernel<<<(NN + 3) / 4, 256, 0, stream>>>(
        (const unsigned short*)h8, row2_start, row2_deg, csr2_src, csr_w,
        b3, g3, be3, m3, v3, bufB, NN);

    // ---- pool (two-phase) + head ----
    pool_partial_kernel<<<GG * PSPLIT, 128, 0, stream>>>(bufB, batch, ppart);
    head_kernel<<<GG, 128, 0, stream>>>(ppart, batch, fw, fb, g4, be4, m4, v4,
                                        l1w, l1b, l2w, l2b, (float*)d_out);
}